// Round 2
// baseline (8034.617 us; speedup 1.0000x reference)
//
#include <hip/hip_runtime.h>
#include <hip/hip_bf16.h>
#include <math.h>

// Problem constants
#define IMGS 3          // B*V
#define H0 256
#define W0 320
#define H1 128
#define W1 160
#define FHh 64
#define FWw 80
#define NPIX 5120       // FHh*FWw
#define ND 128
#define FC 32

// ---------------- helpers ----------------
__device__ inline float ldx(const float* p) { return *p; }
__device__ inline float ldx(const __hip_bfloat16* p) { return __bfloat162float(*p); }
__device__ inline void stx(float* p, float v) { *p = v; }
__device__ inline void stx(__hip_bfloat16* p, float v) { *p = __float2bfloat16(v); }

__device__ inline void inv3(const float* a, float* o) {
    float det = a[0]*(a[4]*a[8]-a[5]*a[7]) - a[1]*(a[3]*a[8]-a[5]*a[6]) + a[2]*(a[3]*a[7]-a[4]*a[6]);
    float id = 1.f/det;
    o[0]=(a[4]*a[8]-a[5]*a[7])*id; o[1]=(a[2]*a[7]-a[1]*a[8])*id; o[2]=(a[1]*a[5]-a[2]*a[4])*id;
    o[3]=(a[5]*a[6]-a[3]*a[8])*id; o[4]=(a[0]*a[8]-a[2]*a[6])*id; o[5]=(a[2]*a[3]-a[0]*a[5])*id;
    o[6]=(a[3]*a[7]-a[4]*a[6])*id; o[7]=(a[1]*a[6]-a[0]*a[7])*id; o[8]=(a[0]*a[4]-a[1]*a[3])*id;
}
__device__ inline void mm3(const float* A, const float* B, float* C) {
    for (int i=0;i<3;i++) for (int j=0;j<3;j++)
        C[i*3+j] = A[i*3+0]*B[0*3+j] + A[i*3+1]*B[1*3+j] + A[i*3+2]*B[2*3+j];
}
__device__ inline void mv3(const float* A, const float* x, float* y) {
    for (int i=0;i<3;i++) y[i] = A[i*3+0]*x[0]+A[i*3+1]*x[1]+A[i*3+2]*x[2];
}

// su layout (floats): [v*12+0..8]=M_v  [v*12+9..11]=b_v  [48..175]=depths  [176]=ds [177]=di
__global__ void k_setup(const float* __restrict__ cam, float* __restrict__ su) {
    if (threadIdx.x != 0 || blockIdx.x != 0) return;
    auto at = [&](int v,int e,int i,int j){ return cam[(v*2+e)*16 + i*4 + j]; };
    float R0[9], K0[9], t0[3], iR0[9], iK0[9];
    for (int i=0;i<3;i++){
        for (int j=0;j<3;j++){ R0[i*3+j]=at(0,0,i,j); K0[i*3+j]=at(0,1,i,j); }
        t0[i]=at(0,0,i,3);
    }
    inv3(R0,iR0); inv3(K0,iK0);
    float ds = at(0,1,3,0), di = at(0,1,3,1), de = at(0,1,3,3);
    for (int d=0; d<ND; d++) su[48+d] = ds + (de-ds)*(float)d/(float)(ND-1);
    su[176]=ds; su[177]=di;
    for (int v=0; v<3; v++){
        float Rv[9], Kv[9], tv[3];
        for (int i=0;i<3;i++){
            for (int j=0;j<3;j++){ Rv[i*3+j]=at(v,0,i,j); Kv[i*3+j]=at(v,1,i,j); }
            tv[i]=at(v,0,i,3);
        }
        float A[9], KA[9], M[9];
        mm3(Rv, iR0, A); mm3(Kv, A, KA); mm3(KA, iK0, M);
        float At0[3], tmp[3], bv[3];
        mv3(A, t0, At0);
        for (int i=0;i<3;i++) tmp[i]=tv[i]-At0[i];
        mv3(Kv, tmp, bv);
        for (int i=0;i<9;i++) su[v*12+i]=M[i];
        for (int i=0;i<3;i++) su[v*12+9+i]=bv[i];
    }
}

// ---------------- feature extractor ----------------
// grid.y = img*Cout+co ; grid.x covers Hout*Wout ; dynamic LDS = Cin*9 floats (this co's weights)
__global__ __launch_bounds__(256) void k_conv3x3(
    const float* __restrict__ in, const float* __restrict__ w, const float* __restrict__ bias,
    float* __restrict__ out, int Cin, int Hin, int Win, int Cout, int Hout, int Wout, int stride)
{
    int img = blockIdx.y / Cout, co = blockIdx.y % Cout;
    extern __shared__ float wsm[];
    for (int i = threadIdx.x; i < Cin*9; i += 256) wsm[i] = w[co*Cin*9 + i];
    __syncthreads();
    int p = blockIdx.x*256 + threadIdx.x;
    if (p >= Hout*Wout) return;
    int oy = p / Wout, ox = p - oy*Wout;
    const float* ib = in + (size_t)img*Cin*Hin*Win;
    float acc = bias ? bias[co] : 0.f;
    for (int ky=0; ky<3; ky++){
        int iy = oy*stride - 1 + ky;
        if ((unsigned)iy >= (unsigned)Hin) continue;
        for (int kx=0; kx<3; kx++){
            int ix = ox*stride - 1 + kx;
            if ((unsigned)ix >= (unsigned)Win) continue;
            const float* ip = ib + (size_t)iy*Win + ix;
            const float* wp = wsm + ky*3 + kx;
            for (int ci=0; ci<Cin; ci++)
                acc = fmaf(wp[ci*9], ip[(size_t)ci*Hin*Win], acc);
        }
    }
    out[((size_t)img*Cout + co)*Hout*Wout + p] = acc;
}

// one block per (img,group); group region is contiguous Cg*HW floats
__global__ __launch_bounds__(256) void k_gnstats(
    const float* __restrict__ x, float* __restrict__ stats, int Cg, int HW)
{
    const float* p = x + (size_t)blockIdx.x * Cg * HW;
    int M = Cg*HW;
    float s1=0.f, s2=0.f;
    for (int i=threadIdx.x; i<M; i+=256){ float v=p[i]; s1+=v; s2=fmaf(v,v,s2); }
    __shared__ float a1[256], a2[256];
    a1[threadIdx.x]=s1; a2[threadIdx.x]=s2; __syncthreads();
    for (int s=128; s>0; s>>=1){
        if (threadIdx.x < s){ a1[threadIdx.x]+=a1[threadIdx.x+s]; a2[threadIdx.x]+=a2[threadIdx.x+s]; }
        __syncthreads();
    }
    if (threadIdx.x==0){
        float mean = a1[0]/(float)M;
        float var  = a2[0]/(float)M - mean*mean;
        stats[blockIdx.x*2]   = mean;
        stats[blockIdx.x*2+1] = rsqrtf(var + 1e-5f);
    }
}

__global__ __launch_bounds__(256) void k_gnapply(
    float* __restrict__ x, const float* __restrict__ stats,
    const float* __restrict__ gamma, const float* __restrict__ beta,
    int C, int HW, int CgHW, int total)
{
    int i = blockIdx.x*256 + threadIdx.x;
    if (i >= total) return;
    int ch  = (i / HW) % C;
    int grp = i / CgHW;
    float mean = stats[grp*2], rstd = stats[grp*2+1];
    float v = (x[i]-mean)*rstd*gamma[ch] + beta[ch];
    x[i] = fmaxf(v, 0.f);
}

// feats (img,c,n) -> (img,n,c) for vectorized channel-contiguous sampling
__global__ __launch_bounds__(256) void k_transpose(
    const float* __restrict__ f, float* __restrict__ ft)
{
    int i = blockIdx.x*256 + threadIdx.x;
    if (i >= IMGS*FC*NPIX) return;
    int n = i % NPIX;
    int c = (i / NPIX) % FC;
    int im = i / (FC*NPIX);
    ft[((size_t)im*NPIX + n)*FC + c] = f[i];
}

// ---------------- warp + cost volume ----------------
template<typename TO>
__global__ __launch_bounds__(256) void k_warpcost(
    const float* __restrict__ ft, const float* __restrict__ su, TO* __restrict__ xb)
{
    int t = blockIdx.x*256 + threadIdx.x;
    int d = t / NPIX, n = t - d*NPIX;
    int py = n / FWw, px = n - py*FWw;
    float u = px + 0.5f, v = py + 0.5f;
    float depth = su[48 + d];
    float s1[FC], s2[FC], samp[FC];
    const float* f0 = ft + (size_t)n*FC;   // view 0: ref feature broadcast
#pragma unroll
    for (int c=0;c<FC;c++){ float f = f0[c]; s1[c] = f; s2[c] = f*f; }
    for (int vv=1; vv<3; vv++){
        const float* m = su + vv*12;
        float wx = fmaf(fmaf(m[0],u,fmaf(m[1],v,m[2])), depth, m[9]);
        float wy = fmaf(fmaf(m[3],u,fmaf(m[4],v,m[5])), depth, m[10]);
        float wz = fmaf(fmaf(m[6],u,fmaf(m[7],v,m[8])), depth, m[11]);
        float iz = 1.f/(wz + 1e-9f);
        float ix = wx*iz - 0.5f, iy = wy*iz - 0.5f;
        float x0 = floorf(ix), y0 = floorf(iy);
#pragma unroll
        for (int c=0;c<FC;c++) samp[c] = 0.f;
        const float* fv = ft + (size_t)vv*NPIX*FC;
        for (int dy=0; dy<2; dy++){
            for (int dx=0; dx<2; dx++){
                float xc = x0+(float)dx, yc = y0+(float)dy;
                if (xc < 0.f || xc > (float)(FWw-1) || yc < 0.f || yc > (float)(FHh-1)) continue;
                float wgt = (1.f - fabsf(ix-xc))*(1.f - fabsf(iy-yc));
                const float* fp = fv + ((size_t)((int)yc)*FWw + (int)xc)*FC;
#pragma unroll
                for (int c=0;c<FC;c++) samp[c] = fmaf(fp[c], wgt, samp[c]);
            }
        }
#pragma unroll
        for (int c=0;c<FC;c++){ s1[c] += samp[c]; s2[c] = fmaf(samp[c], samp[c], s2[c]); }
    }
    TO* ob = xb + (size_t)d*FC*NPIX + n;
#pragma unroll
    for (int c=0;c<FC;c++){
        float m1 = s1[c]*(1.f/3.f);
        float cost = s2[c]*(1.f/3.f) - m1*m1;
        stx(ob + (size_t)c*NPIX, -cost);   // GRU input is -cost
    }
}

// ---------------- GRU scan ----------------
// grid = (NPIX/256, CH); weights (CH, CX+CH, 3, 3), x first then h in channel concat
template<typename TX, int CX, int CH>
__global__ __launch_bounds__(256) void k_gru_zr(
    const TX* __restrict__ x, const float* __restrict__ h,
    const float* __restrict__ wz, const float* __restrict__ bz,
    const float* __restrict__ wr, const float* __restrict__ br,
    float* __restrict__ zg, float* __restrict__ rh)
{
    int n = blockIdx.x*256 + threadIdx.x;
    int co = blockIdx.y;
    int py = n / FWw, px = n - py*FWw;
    const float* wzc = wz + (size_t)co*(CX+CH)*9;
    const float* wrc = wr + (size_t)co*(CX+CH)*9;
    float az = bz[co], ar = br[co];
#pragma unroll
    for (int ky=0; ky<3; ky++){
        int iy = py + ky - 1;
        if ((unsigned)iy >= (unsigned)FHh) continue;
#pragma unroll
        for (int kx=0; kx<3; kx++){
            int ixp = px + kx - 1;
            if ((unsigned)ixp >= (unsigned)FWw) continue;
            int off = iy*FWw + ixp;
            int k = ky*3 + kx;
#pragma unroll
            for (int ci=0; ci<CX; ci++){
                float vx = ldx(x + (size_t)ci*NPIX + off);
                az = fmaf(wzc[ci*9+k], vx, az);
                ar = fmaf(wrc[ci*9+k], vx, ar);
            }
#pragma unroll
            for (int ci=0; ci<CH; ci++){
                float vh = h[(size_t)ci*NPIX + off];
                az = fmaf(wzc[(CX+ci)*9+k], vh, az);
                ar = fmaf(wrc[(CX+ci)*9+k], vh, ar);
            }
        }
    }
    float z = 1.f/(1.f + expf(-az));
    float r = 1.f/(1.f + expf(-ar));
    zg[(size_t)co*NPIX + n] = z;
    rh[(size_t)co*NPIX + n] = r * h[(size_t)co*NPIX + n];
}

template<typename TX, int CX, int CH>
__global__ __launch_bounds__(256) void k_gru_c(
    const TX* __restrict__ x, const float* __restrict__ rh, const float* __restrict__ hold,
    const float* __restrict__ wc, const float* __restrict__ bc,
    const float* __restrict__ zg, float* __restrict__ hnew)
{
    int n = blockIdx.x*256 + threadIdx.x;
    int co = blockIdx.y;
    int py = n / FWw, px = n - py*FWw;
    const float* wcc = wc + (size_t)co*(CX+CH)*9;
    float ac = bc[co];
#pragma unroll
    for (int ky=0; ky<3; ky++){
        int iy = py + ky - 1;
        if ((unsigned)iy >= (unsigned)FHh) continue;
#pragma unroll
        for (int kx=0; kx<3; kx++){
            int ixp = px + kx - 1;
            if ((unsigned)ixp >= (unsigned)FWw) continue;
            int off = iy*FWw + ixp;
            int k = ky*3 + kx;
#pragma unroll
            for (int ci=0; ci<CX; ci++){
                float vx = ldx(x + (size_t)ci*NPIX + off);
                ac = fmaf(wcc[ci*9+k], vx, ac);
            }
#pragma unroll
            for (int ci=0; ci<CH; ci++){
                float vh = rh[(size_t)ci*NPIX + off];
                ac = fmaf(wcc[(CX+ci)*9+k], vh, ac);
            }
        }
    }
    float cg = tanhf(ac);
    float z = zg[(size_t)co*NPIX + n];
    hnew[(size_t)co*NPIX + n] = z*hold[(size_t)co*NPIX + n] + (1.f - z)*cg;
}

__global__ __launch_bounds__(256) void k_prob(
    const float* __restrict__ h3, const float* __restrict__ w, const float* __restrict__ b,
    float* __restrict__ reg)
{
    int n = blockIdx.x*256 + threadIdx.x;
    int py = n / FWw, px = n - py*FWw;
    float a = b[0];
#pragma unroll
    for (int ky=0; ky<3; ky++){
        int iy = py + ky - 1;
        if ((unsigned)iy >= (unsigned)FHh) continue;
#pragma unroll
        for (int kx=0; kx<3; kx++){
            int ixp = px + kx - 1;
            if ((unsigned)ixp >= (unsigned)FWw) continue;
            int off = iy*FWw + ixp;
            int k = ky*3 + kx;
            a = fmaf(w[k],   h3[off],        a);
            a = fmaf(w[9+k], h3[NPIX+off],   a);
        }
    }
    reg[n] = a;
}

// ---------------- softmax / depth regression ----------------
// NOTE: reference output dtype is float32 (all-f32 pipeline) -> d_out is float*.
// Round-1 failure signature (absmax = 592 - 0.03) proved the harness reads f32;
// bf16 writes were being reinterpreted as packed pairs.
__global__ __launch_bounds__(256) void k_final(
    const float* __restrict__ reg, const float* __restrict__ su, float* __restrict__ out)
{
    int n = blockIdx.x*256 + threadIdx.x;
    if (n >= NPIX) return;
    float m = -1e30f;
    for (int d=0; d<ND; d++) m = fmaxf(m, reg[(size_t)d*NPIX + n]);
    float s = 0.f, acc = 0.f;
    for (int d=0; d<ND; d++){
        float e = expf(reg[(size_t)d*NPIX + n] - m);
        s += e;
        acc = fmaf(e, su[48+d], acc);
    }
    float inv_s = 1.f/s;
    float pred = acc * inv_s;
    float ds = su[176], di = su[177];
    int i0 = (int)floorf((pred - ds)/di);
    float pm = 0.f;
    for (int k=0; k<4; k++){
        int g = min(max(i0 - 1 + k, 0), ND-1);
        pm += expf(reg[(size_t)g*NPIX + n] - m);
    }
    pm *= inv_s;
    out[n]        = pred;
    out[NPIX + n] = pm;
}

// ---------------- host orchestration ----------------
extern "C" void kernel_launch(void* const* d_in, const int* in_sizes, int n_in,
                              void* d_out, int out_size, void* d_ws, size_t ws_size,
                              hipStream_t stream)
{
    (void)in_sizes; (void)n_in; (void)out_size;
    const float* img   = (const float*)d_in[0];
    const float* cam   = (const float*)d_in[1];
    const float* fe_w0 = (const float*)d_in[2];
    const float* fe_g0 = (const float*)d_in[3];
    const float* fe_b0 = (const float*)d_in[4];
    const float* fe_w1 = (const float*)d_in[5];
    const float* fe_g1 = (const float*)d_in[6];
    const float* fe_b1 = (const float*)d_in[7];
    const float* fe_w2 = (const float*)d_in[8];
    const float* fe_g2 = (const float*)d_in[9];
    const float* fe_b2 = (const float*)d_in[10];
    const float* fe_w3 = (const float*)d_in[11];
    const float* fe_b3 = (const float*)d_in[12];
    const float* gw[3][3]; const float* gb[3][3];
    for (int i=0;i<3;i++) for (int g=0; g<3; g++){
        gw[i][g] = (const float*)d_in[13 + i*6 + g*2];
        gb[i][g] = (const float*)d_in[13 + i*6 + g*2 + 1];
    }
    const float* prob_w = (const float*)d_in[31];
    const float* prob_b = (const float*)d_in[32];
    float* out = (float*)d_out;

    // workspace layout
    char* base = (char*)d_ws;
    size_t off = 0;
    auto alloc = [&](size_t bytes)->char*{
        char* p = base + off; off += (bytes + 255) & ~(size_t)255; return p;
    };
    float* su     = (float*)alloc(256*4);
    float* stats  = (float*)alloc(64*4);
    float* buf0   = (float*)alloc((size_t)IMGS*8*H0*W0*4);
    float* buf1   = (float*)alloc((size_t)IMGS*16*H1*W1*4);
    float* buf2   = (float*)alloc((size_t)IMGS*32*NPIX*4);
    float* feats  = (float*)alloc((size_t)IMGS*32*NPIX*4);
    float* featst = (float*)alloc((size_t)IMGS*NPIX*FC*4);
    float* reg    = (float*)alloc((size_t)ND*NPIX*4);
    float* h1[2]; h1[0]=(float*)alloc(16*NPIX*4); h1[1]=(float*)alloc(16*NPIX*4);
    float* h2[2]; h2[0]=(float*)alloc(4*NPIX*4);  h2[1]=(float*)alloc(4*NPIX*4);
    float* h3[2]; h3[0]=(float*)alloc(2*NPIX*4);  h3[1]=(float*)alloc(2*NPIX*4);
    float* zg0 = (float*)alloc(16*NPIX*4);
    float* rh0 = (float*)alloc(16*NPIX*4);
    float* zg1 = (float*)alloc(4*NPIX*4);
    float* rh1 = (float*)alloc(4*NPIX*4);
    float* zg2 = (float*)alloc(2*NPIX*4);
    float* rh2 = (float*)alloc(2*NPIX*4);
    size_t off_common = off;
    // cost volume: f32 if workspace allows, else bf16
    bool xf32 = (ws_size >= off_common + (size_t)ND*FC*NPIX*4);
    void* xbuf = (void*)(base + off_common);

    // zero initial hidden states (ws is re-poisoned before every call)
    hipMemsetAsync(h1[0], 0, 16*NPIX*4, stream);
    hipMemsetAsync(h2[0], 0, 4*NPIX*4, stream);
    hipMemsetAsync(h3[0], 0, 2*NPIX*4, stream);

    k_setup<<<1, 64, 0, stream>>>(cam, su);

    // ---- feature extraction ----
    // L0: 3->8, 256x320, GN(1)+ReLU
    k_conv3x3<<<dim3((H0*W0+255)/256, IMGS*8), 256, 3*9*4, stream>>>(
        img, fe_w0, nullptr, buf0, 3, H0, W0, 8, H0, W0, 1);
    k_gnstats<<<IMGS*1, 256, 0, stream>>>(buf0, stats, 8, H0*W0);
    k_gnapply<<<(IMGS*8*H0*W0+255)/256, 256, 0, stream>>>(
        buf0, stats, fe_g0, fe_b0, 8, H0*W0, 8*H0*W0, IMGS*8*H0*W0);
    // L1: 8->16 s2, 128x160, GN(2)+ReLU
    k_conv3x3<<<dim3((H1*W1+255)/256, IMGS*16), 256, 8*9*4, stream>>>(
        buf0, fe_w1, nullptr, buf1, 8, H0, W0, 16, H1, W1, 2);
    k_gnstats<<<IMGS*2, 256, 0, stream>>>(buf1, stats, 8, H1*W1);
    k_gnapply<<<(IMGS*16*H1*W1+255)/256, 256, 0, stream>>>(
        buf1, stats, fe_g1, fe_b1, 16, H1*W1, 8*H1*W1, IMGS*16*H1*W1);
    // L2: 16->32 s2, 64x80, GN(4)+ReLU
    k_conv3x3<<<dim3((NPIX+255)/256, IMGS*32), 256, 16*9*4, stream>>>(
        buf1, fe_w2, nullptr, buf2, 16, H1, W1, 32, FHh, FWw, 2);
    k_gnstats<<<IMGS*4, 256, 0, stream>>>(buf2, stats, 8, NPIX);
    k_gnapply<<<(IMGS*32*NPIX+255)/256, 256, 0, stream>>>(
        buf2, stats, fe_g2, fe_b2, 32, NPIX, 8*NPIX, IMGS*32*NPIX);
    // L3: 32->32 + bias, no norm
    k_conv3x3<<<dim3((NPIX+255)/256, IMGS*32), 256, 32*9*4, stream>>>(
        buf2, fe_w3, fe_b3, feats, 32, FHh, FWw, 32, FHh, FWw, 1);
    k_transpose<<<(IMGS*FC*NPIX+255)/256, 256, 0, stream>>>(feats, featst);

    // ---- warp + cost volume ----
    if (xf32) {
        k_warpcost<float><<<ND*NPIX/256, 256, 0, stream>>>(featst, su, (float*)xbuf);
    } else {
        k_warpcost<__hip_bfloat16><<<ND*NPIX/256, 256, 0, stream>>>(featst, su, (__hip_bfloat16*)xbuf);
    }

    // ---- GRU scan over depth ----
    for (int d=0; d<ND; d++){
        int cur = d & 1, nxt = cur ^ 1;
        if (xf32) {
            const float* xd = (const float*)xbuf + (size_t)d*FC*NPIX;
            k_gru_zr<float,32,16><<<dim3(NPIX/256,16),256,0,stream>>>(
                xd, h1[cur], gw[0][0], gb[0][0], gw[0][1], gb[0][1], zg0, rh0);
            k_gru_c<float,32,16><<<dim3(NPIX/256,16),256,0,stream>>>(
                xd, rh0, h1[cur], gw[0][2], gb[0][2], zg0, h1[nxt]);
        } else {
            const __hip_bfloat16* xd = (const __hip_bfloat16*)xbuf + (size_t)d*FC*NPIX;
            k_gru_zr<__hip_bfloat16,32,16><<<dim3(NPIX/256,16),256,0,stream>>>(
                xd, h1[cur], gw[0][0], gb[0][0], gw[0][1], gb[0][1], zg0, rh0);
            k_gru_c<__hip_bfloat16,32,16><<<dim3(NPIX/256,16),256,0,stream>>>(
                xd, rh0, h1[cur], gw[0][2], gb[0][2], zg0, h1[nxt]);
        }
        k_gru_zr<float,16,4><<<dim3(NPIX/256,4),256,0,stream>>>(
            h1[nxt], h2[cur], gw[1][0], gb[1][0], gw[1][1], gb[1][1], zg1, rh1);
        k_gru_c<float,16,4><<<dim3(NPIX/256,4),256,0,stream>>>(
            h1[nxt], rh1, h2[cur], gw[1][2], gb[1][2], zg1, h2[nxt]);
        k_gru_zr<float,4,2><<<dim3(NPIX/256,2),256,0,stream>>>(
            h2[nxt], h3[cur], gw[2][0], gb[2][0], gw[2][1], gb[2][1], zg2, rh2);
        k_gru_c<float,4,2><<<dim3(NPIX/256,2),256,0,stream>>>(
            h2[nxt], rh2, h3[cur], gw[2][2], gb[2][2], zg2, h3[nxt]);
        k_prob<<<dim3(NPIX/256),256,0,stream>>>(h3[nxt], prob_w, prob_b, reg + (size_t)d*NPIX);
    }

    // ---- softmax + depth regression + prob map ----
    k_final<<<NPIX/256, 256, 0, stream>>>(reg, su, out);
}